// Round 12
// baseline (243.642 us; speedup 1.0000x reference)
//
#include <hip/hip_runtime.h>
#include <hip/hip_bf16.h>
#include <cstdint>
#include <cstddef>

#define BB 16
#define CC 256
#define LL 4096
#define KNUM 1024
#define NFRM (BB * LL)      // 65536 frames
#define NTILE (NFRM / 32)   // 2048 blocks of 32 frames
#define QCAP 1536           // block-level candidate queue capacity
#define BAND 0.012f

static const size_t NOUT = (size_t)BB * CC * LL;   // 16777216 floats

typedef __attribute__((ext_vector_type(8))) short short8v;
typedef __attribute__((ext_vector_type(4))) short short4v;
typedef __attribute__((ext_vector_type(4))) float f32x4;
typedef __attribute__((ext_vector_type(8))) __bf16 bf16x8;

__device__ __forceinline__ f32x4 mfma16(short8v a, short8v b, f32x4 c) {
    return __builtin_amdgcn_mfma_f32_16x16x32_bf16(
        __builtin_bit_cast(bf16x8, a), __builtin_bit_cast(bf16x8, b), c, 0, 0, 0);
}

__device__ __forceinline__ short bf16bits(float v) {
    __hip_bfloat16 h = __float2bfloat16(v);
    return *reinterpret_cast<short*>(&h);
}

// pack (sim, k) so that u64-max == (greater sim, else lower k)
__device__ __forceinline__ unsigned long long packkey(float s, int k) {
    unsigned int sb = __float_as_uint(s);
    sb = (sb & 0x80000000u) ? ~sb : (sb | 0x80000000u);
    return ((unsigned long long)sb << 32) | (unsigned long long)(1023 - k);
}

// monotone float<->uint for LDS atomicMax over floats (any sign)
__device__ __forceinline__ unsigned int fflip(float s) {
    unsigned int u = __float_as_uint(s);
    return (u & 0x80000000u) ? ~u : (u | 0x80000000u);
}
__device__ __forceinline__ float funflip(unsigned int u) {
    return __uint_as_float((u & 0x80000000u) ? (u ^ 0x80000000u) : ~u);
}

// ------------------------------------------------------- K1: codebook norms
// BYTE-IDENTICAL math to rounds 3-11.
__global__ void k_cbnorm(const float* __restrict__ cb, float* __restrict__ en,
                         float* __restrict__ enorm2, short* __restrict__ enh) {
    __shared__ double wsum[4];
    const int k = blockIdx.x, c = threadIdx.x;
    float v = cb[(size_t)k * CC + c];
    double d = (double)v * (double)v;
#pragma unroll
    for (int m = 32; m >= 1; m >>= 1) d += __shfl_down(d, m);
    const int wv = c >> 6, ln = c & 63;
    if (ln == 0) wsum[wv] = d;
    __syncthreads();
    const double tot = wsum[0] + wsum[1] + wsum[2] + wsum[3];
    const float s32 = (float)tot;
    const float rn = 1.0f / sqrtf(s32 + 1e-12f);
    const float e = v * rn;                 // one fp32 rounding, like ref
    en[(size_t)k * CC + c] = e;
    enh[(size_t)k * CC + c] = bf16bits(e);
    double e2 = (double)e * (double)e;
#pragma unroll
    for (int m = 32; m >= 1; m >>= 1) e2 += __shfl_down(e2, m);
    __syncthreads();
    if (ln == 0) wsum[wv] = e2;
    __syncthreads();
    if (c == 0) enorm2[k] = (float)(wsum[0] + wsum[1] + wsum[2] + wsum[3]);
}

// ---------- K2 (fused): per-frame fp64 norm + rn + transpose to bf16 xnh
__global__ __launch_bounds__(256, 2) void k_xt2(
    const float* __restrict__ x, float* __restrict__ rnx,
    float* __restrict__ nxn, short* __restrict__ xnh) {
    __shared__ short T[64][260];
    __shared__ double red[4][64];
    __shared__ float rns[64];
    const int tid = threadIdx.x;
    const int b = blockIdx.x >> 6;
    const int l0 = (blockIdx.x & 63) << 6;
    const int l = tid & 63, seg = tid >> 6;
    const float* xp = x + (size_t)b * CC * LL + l0 + l;

    double s0 = 0.0, s1 = 0.0, s2 = 0.0, s3 = 0.0;
#pragma unroll 4
    for (int i = 0; i < 64; i += 4) {
        int c = seg * 64 + i;
        float v0 = xp[(size_t)(c + 0) * LL];
        float v1 = xp[(size_t)(c + 1) * LL];
        float v2 = xp[(size_t)(c + 2) * LL];
        float v3 = xp[(size_t)(c + 3) * LL];
        s0 += (double)v0 * v0; s1 += (double)v1 * v1;
        s2 += (double)v2 * v2; s3 += (double)v3 * v3;
    }
    red[seg][l] = (s0 + s1) + (s2 + s3);
    __syncthreads();
    if (tid < 64) {
        double tot = (red[0][tid] + red[1][tid]) + (red[2][tid] + red[3][tid]);
        const float s32 = (float)tot;
        const float rn = 1.0f / sqrtf(s32 + 1e-12f);
        const int f = b * LL + l0 + tid;
        rnx[f] = rn;
        nxn[f] = s32 * rn * rn;
        rns[tid] = rn;
    }
    __syncthreads();
    const float rn = rns[l];

#pragma unroll 8
    for (int i = 0; i < 64; ++i) {
        int c = seg * 64 + i;
        T[l][c] = bf16bits(xp[(size_t)c * LL] * rn);
    }
    __syncthreads();
#pragma unroll
    for (int rr = 0; rr < 4; ++rr) {
        int row = rr * 16 + (tid >> 4);
        int cs = (tid & 15) << 4;
        short* dst = xnh + ((size_t)(b * LL + l0 + row)) * 256 + cs;
        short4v p0 = *(const short4v*)&T[row][cs + 0];
        short4v p1 = *(const short4v*)&T[row][cs + 4];
        short4v p2 = *(const short4v*)&T[row][cs + 8];
        short4v p3 = *(const short4v*)&T[row][cs + 12];
        short8v o0, o1;
        o0[0]=p0[0];o0[1]=p0[1];o0[2]=p0[2];o0[3]=p0[3];o0[4]=p1[0];o0[5]=p1[1];o0[6]=p1[2];o0[7]=p1[3];
        o1[0]=p2[0];o1[1]=p2[1];o1[2]=p2[2];o1[3]=p2[3];o1[4]=p3[0];o1[5]=p3[1];o1[6]=p3[2];o1[7]=p3[3];
        *(short8v*)&dst[0] = o0;
        *(short8v*)&dst[8] = o1;
    }
}

// ---------------- K3: bf16 MFMA sim GEMM -> block-local LDS candidate queue
// 32 frames x 1024 k per block (small block -> 4-6 blocks/CU TLP).
// Barrier-free main loop (wave-local prefix max); flush computes per-frame
// TRUE max over the queue and filters to sim >= fmax - BAND (r11 set).
#define BLOAD(dst, kcv, csv)                                                   \
    _Pragma("unroll")                                                          \
    for (int kt = 0; kt < 4; ++kt)                                             \
        dst[kt] = *(const short8v*)&enh[(size_t)((kcv) * 256 + w * 64 +        \
                                                 kt * 16 + lr) * 256 +         \
                                        (csv) * 32 + lg * 8];

__global__ __launch_bounds__(256, 2) void k_cand(
    const short* __restrict__ xnh, const short* __restrict__ enh,
    int* __restrict__ qcnt, int* __restrict__ fcnt,
    unsigned short* __restrict__ qbuf) {
    __shared__ short Alds[32 * 256];       // 16KB, swizzled ^((fr&7)<<3)
    __shared__ unsigned short qd[QCAP];    // 3KB  (fl<<10)|k
    __shared__ float qs[QCAP];             // 6KB  fp32 sims
    __shared__ unsigned int fmaxu[32];
    __shared__ int qn, fn;
    const int tid = threadIdx.x;
    const int w = tid >> 6;
    const int l = tid & 63;
    const int lr = l & 15, lg = l >> 4;
    const int f0 = blockIdx.x << 5;        // 32 frames per block

    // ---- stage A once: 32f x 256c
    {
        short8v areg[4];
#pragma unroll
        for (int i = 0; i < 4; ++i) {
            int idx = i * 256 + tid;
            int fr = idx >> 5, c8 = (idx & 31) << 3;
            areg[i] = *(const short8v*)&xnh[(size_t)(f0 + fr) * 256 + c8];
        }
#pragma unroll
        for (int i = 0; i < 4; ++i) {
            int idx = i * 256 + tid;
            int fr = idx >> 5, c8 = (idx & 31) << 3;
            *(short8v*)&Alds[(fr * 256 + c8) ^ ((fr & 7) << 3)] = areg[i];
        }
    }
    if (tid == 0) { qn = 0; fn = 0; }
    if (tid < 32) fmaxu[tid] = 0;
    __syncthreads();          // the ONLY pre-flush barrier

    float runmax[2][4];
#pragma unroll
    for (int i = 0; i < 2; ++i)
#pragma unroll
        for (int r = 0; r < 4; ++r) runmax[i][r] = -3e38f;

    short8v breg[2][4];
    BLOAD(breg[0], 0, 0);

    for (int kc = 0; kc < 4; ++kc) {
        f32x4 acc[2][4];
#pragma unroll
        for (int ft = 0; ft < 2; ++ft)
#pragma unroll
            for (int kt = 0; kt < 4; ++kt) acc[ft][kt] = (f32x4){0.f, 0.f, 0.f, 0.f};

#pragma unroll
        for (int cs = 0; cs < 8; ++cs) {
            const int cur = cs & 1, nxt = cur ^ 1;
            if (cs < 7) {
                BLOAD(breg[nxt], kc, cs + 1);
            } else if (kc < 3) {
                BLOAD(breg[nxt], kc + 1, 0);
            }
            short8v af[2];
#pragma unroll
            for (int ft = 0; ft < 2; ++ft) {
                int fr = ft * 16 + lr;
                af[ft] = *(const short8v*)&Alds[(fr * 256 + cs * 32 + lg * 8) ^ ((lr & 7) << 3)];
            }
#pragma unroll
            for (int kt = 0; kt < 4; ++kt)
#pragma unroll
                for (int ft = 0; ft < 2; ++ft)
                    acc[ft][kt] = mfma16(af[ft], breg[cur][kt], acc[ft][kt]);
        }

        // ---- epilogue: wave-local prefix max + banded LDS-queue appends
#pragma unroll
        for (int ft = 0; ft < 2; ++ft) {
#pragma unroll
            for (int r = 0; r < 4; ++r) {
                float m = fmaxf(fmaxf(acc[ft][0][r], acc[ft][1][r]),
                                fmaxf(acc[ft][2][r], acc[ft][3][r]));
#pragma unroll
                for (int mm = 1; mm < 16; mm <<= 1) m = fmaxf(m, __shfl_xor(m, mm));
                float rm = fmaxf(runmax[ft][r], m);
                runmax[ft][r] = rm;
                const float thr = rm - BAND;
                const int fl = ft * 16 + lg * 4 + r;
#pragma unroll
                for (int kt = 0; kt < 4; ++kt) {
                    if (acc[ft][kt][r] >= thr) {
                        int kg = kc * 256 + w * 64 + kt * 16 + lr;
                        int slot = atomicAdd(&qn, 1);          // LDS atomic
                        if (slot < QCAP) {
                            qd[slot] = (unsigned short)((fl << 10) | kg);
                            qs[slot] = acc[ft][kt][r];
                        }
                    }
                }
            }
        }
    }

    // ---- flush: per-frame TRUE max over queue, filter, write direct
    __syncthreads();
    const int n = qn;
    if (tid == 0) qcnt[blockIdx.x] = n;
    if (n > QCAP) return;     // overflow (~never): fallback3 does full scan
    for (int i = tid; i < n; i += 256)
        atomicMax(&fmaxu[qd[i] >> 10], fflip(qs[i]));
    __syncthreads();
    for (int i = tid; i < n; i += 256) {
        const float fm = funflip(fmaxu[qd[i] >> 10]);
        if (qs[i] >= fm - BAND) {
            int s = atomicAdd(&fn, 1);
            qbuf[(size_t)blockIdx.x * QCAP + s] = qd[i];
        }
    }
    __syncthreads();
    if (tid == 0) fcnt[blockIdx.x] = fn;
}

// --------- K4: LDS-staged seq-fp32 re-check of the block queue + atomic key
__global__ __launch_bounds__(256, 2) void k_resolve2(
    const float* __restrict__ x, const float* __restrict__ en,
    const float* __restrict__ rnx, const int* __restrict__ qcnt,
    const int* __restrict__ fcnt, const unsigned short* __restrict__ qbuf,
    unsigned long long* __restrict__ pk) {
    __shared__ float xn[32 * 257];     // ~33KB, conflict-free stride
    __shared__ float rns[32];
    const int tid = threadIdx.x;
    const int bid = blockIdx.x;
    const int f0 = bid << 5;
    const int b = f0 >> 12;
    const int l0 = f0 & (LL - 1);
    const float* xb = x + (size_t)b * CC * LL + l0;

    if (qcnt[bid] > QCAP) return;      // overflow block -> k_fallback3 (uniform)
    const int n = fcnt[bid];

    if (tid < 32) rns[tid] = rnx[f0 + tid];
    __syncthreads();
    // vectorized stage: float4 over l (16B/lane)
    {
        const int l4 = (tid & 7) << 2;
        const float r0 = rns[l4 + 0], r1 = rns[l4 + 1];
        const float r2 = rns[l4 + 2], r3 = rns[l4 + 3];
#pragma unroll 4
        for (int it = 0; it < 8; ++it) {
            const int c = it * 32 + (tid >> 3);
            f32x4 v = *(const f32x4*)&xb[(size_t)c * LL + l4];
            xn[(l4 + 0) * 257 + c] = v[0] * r0;
            xn[(l4 + 1) * 257 + c] = v[1] * r1;
            xn[(l4 + 2) * 257 + c] = v[2] * r2;
            xn[(l4 + 3) * 257 + c] = v[3] * r3;
        }
    }
    __syncthreads();
    for (int e = tid; e < n; e += 256) {
        const unsigned short ent = qbuf[(size_t)bid * QCAP + e];
        const int fl = ent >> 10, k = ent & 1023;
        const f32x4* er4 = (const f32x4*)(en + (size_t)k * CC);
        const float* xr = &xn[fl * 257];
        float s = 0.f;
#pragma unroll 8
        for (int c4 = 0; c4 < 64; ++c4) {      // ascending c, sequential FMA
            f32x4 ev = er4[c4];
            s = fmaf(xr[c4 * 4 + 0], ev[0], s);
            s = fmaf(xr[c4 * 4 + 1], ev[1], s);
            s = fmaf(xr[c4 * 4 + 2], ev[2], s);
            s = fmaf(xr[c4 * 4 + 3], ev[3], s);
        }
        atomicMax(&pk[f0 + fl], packkey(s, k));
    }
}

// -------- K4b: queue-overflow fallback (~never): full scan of block's frames
__global__ __launch_bounds__(256) void k_fallback3(
    const float* __restrict__ x, const float* __restrict__ en,
    const float* __restrict__ rnx, const int* __restrict__ qcnt,
    unsigned long long* __restrict__ pk) {
    if (qcnt[blockIdx.x] <= QCAP) return;      // block-uniform early exit
    __shared__ float xr[CC];
    const int tid = threadIdx.x;
    const int f0 = blockIdx.x << 5;
    const int b = f0 >> 12;
    const int l0 = f0 & (LL - 1);
    for (int fl = 0; fl < 32; ++fl) {
        const int f = f0 + fl;
        __syncthreads();
        xr[tid] = x[((size_t)b * CC + tid) * LL + (l0 + fl)] * rnx[f];
        __syncthreads();
#pragma unroll
        for (int j = 0; j < 4; ++j) {
            const int k = tid + j * 256;
            const f32x4* er4 = (const f32x4*)(en + (size_t)k * CC);
            float s = 0.f;
#pragma unroll 8
            for (int c4 = 0; c4 < 64; ++c4) {
                f32x4 ev = er4[c4];
                s = fmaf(xr[c4 * 4 + 0], ev[0], s);
                s = fmaf(xr[c4 * 4 + 1], ev[1], s);
                s = fmaf(xr[c4 * 4 + 2], ev[2], s);
                s = fmaf(xr[c4 * 4 + 3], ev[3], s);
            }
            atomicMax(&pk[f], packkey(s, k));
        }
    }
}

// ---------------- K5: unpack winners, gather -> out, loss reduce
__global__ void k_gather(const float* __restrict__ en,
                         const unsigned long long* __restrict__ pk,
                         const float* __restrict__ nxn,
                         const float* __restrict__ enorm2, float* __restrict__ out,
                         float* __restrict__ loss) {
    __shared__ float ens[32][257];
    __shared__ int lidx[32];
    __shared__ float ssim[32];
    const int tid = threadIdx.x;
    const int b = blockIdx.x >> 7;
    const int l0 = (blockIdx.x & 127) << 5;
    const int fbase = b * LL + l0;
    if (tid < 32) {
        unsigned long long v = pk[fbase + tid];
        lidx[tid] = 1023 - (int)(v & 1023ull);
        unsigned int hi = (unsigned int)(v >> 32);
        unsigned int sb = (hi & 0x80000000u) ? (hi ^ 0x80000000u) : ~hi;
        ssim[tid] = __uint_as_float(sb);
    }
    __syncthreads();
    for (int j = 0; j < 32; ++j)
        ens[j][tid] = en[(size_t)lidx[j] * CC + tid];
    __syncthreads();
    const int jj = tid & 31;
    const int c0 = (tid >> 5) << 5;
    float* ob = out + (size_t)b * CC * LL + l0;
#pragma unroll 4
    for (int ci = 0; ci < 32; ++ci) {
        int c = c0 + ci;
        ob[(size_t)c * LL + jj] = ens[jj][c];
    }
    float part = 0.f;
    if (tid < 32) {
        int f = fbase + tid;
        part = nxn[f] + enorm2[lidx[tid]] - 2.0f * ssim[tid];
    }
    if (tid < 64) {
#pragma unroll
        for (int m = 32; m >= 1; m >>= 1) part += __shfl_xor(part, m);
        if (tid == 0) atomicAdd(loss, part * (1.25f / 16777216.f));
    }
}

// ------------------------------------------------------------------- launch
extern "C" void kernel_launch(void* const* d_in, const int* in_sizes, int n_in,
                              void* d_out, int out_size, void* d_ws, size_t ws_size,
                              hipStream_t stream) {
    const float* x = (const float*)d_in[0];
    const float* cb = (const float*)d_in[1];
    float* out = (float*)d_out;
    char* ws = (char*)d_ws;
    char* ob = (char*)d_out;

    // ws scratch (~2.7 MB)
    float* en     = (float*)(ws);                    // 1 MB
    float* enorm2 = (float*)(ws + 0x100000);         // 4 KB
    float* rnx    = (float*)(ws + 0x101000);         // 256 KB
    float* nxn    = (float*)(ws + 0x141000);         // 256 KB
    short* enh    = (short*)(ws + 0x181000);         // 512 KB
    unsigned long long* pk = (unsigned long long*)(ws + 0x201000);  // 512 KB
    int*   qcnt   = (int*)(ws + 0x281000);           // 8 KB (2048)
    int*   fcnt   = (int*)(ws + 0x283000);           // 8 KB (2048)

    // big scratch inside d_out (64 MB); gather (last) overwrites it.
    short*          xnh  = (short*)ob;                       // 32 MB
    unsigned short* qbuf = (unsigned short*)(ob + 33554432); // 6 MB (2048*QCAP*2B)

    hipMemsetAsync(pk, 0, NFRM * sizeof(unsigned long long), stream);
    hipMemsetAsync(out + NOUT, 0, sizeof(float), stream);

    k_cbnorm<<<KNUM, 256, 0, stream>>>(cb, en, enorm2, enh);
    k_xt2<<<BB * (LL / 64), 256, 0, stream>>>(x, rnx, nxn, xnh);
    k_cand<<<NTILE, 256, 0, stream>>>(xnh, enh, qcnt, fcnt, qbuf);
    k_resolve2<<<NTILE, 256, 0, stream>>>(x, en, rnx, qcnt, fcnt, qbuf, pk);
    k_fallback3<<<NTILE, 256, 0, stream>>>(x, en, rnx, qcnt, pk);
    k_gather<<<BB * (LL / 32), 256, 0, stream>>>(en, pk, nxn, enorm2, out, out + NOUT);
}

// Round 13
// 211.843 us; speedup vs baseline: 1.1501x; 1.1501x over previous
//
#include <hip/hip_runtime.h>
#include <hip/hip_bf16.h>
#include <cstdint>
#include <cstddef>

#define BB 16
#define CC 256
#define LL 4096
#define KNUM 1024
#define NFRM (BB * LL)      // 65536 frames
#define QCAP 2048           // block-level candidate queue capacity
#define BAND 0.012f

static const size_t NOUT = (size_t)BB * CC * LL;   // 16777216 floats

typedef __attribute__((ext_vector_type(8))) short short8v;
typedef __attribute__((ext_vector_type(4))) short short4v;
typedef __attribute__((ext_vector_type(4))) float f32x4;
typedef __attribute__((ext_vector_type(8))) __bf16 bf16x8;

__device__ __forceinline__ f32x4 mfma16(short8v a, short8v b, f32x4 c) {
    return __builtin_amdgcn_mfma_f32_16x16x32_bf16(
        __builtin_bit_cast(bf16x8, a), __builtin_bit_cast(bf16x8, b), c, 0, 0, 0);
}

__device__ __forceinline__ short bf16bits(float v) {
    __hip_bfloat16 h = __float2bfloat16(v);
    return *reinterpret_cast<short*>(&h);
}

// pack (sim, k) so that u64-max == (greater sim, else lower k)
__device__ __forceinline__ unsigned long long packkey(float s, int k) {
    unsigned int sb = __float_as_uint(s);
    sb = (sb & 0x80000000u) ? ~sb : (sb | 0x80000000u);
    return ((unsigned long long)sb << 32) | (unsigned long long)(1023 - k);
}

// monotone float<->uint for LDS atomicMax over floats (any sign)
__device__ __forceinline__ unsigned int fflip(float s) {
    unsigned int u = __float_as_uint(s);
    return (u & 0x80000000u) ? ~u : (u | 0x80000000u);
}
__device__ __forceinline__ float funflip(unsigned int u) {
    return __uint_as_float((u & 0x80000000u) ? (u ^ 0x80000000u) : ~u);
}

// ------------------------------------------------------- K1: codebook norms
// BYTE-IDENTICAL math to rounds 3-12.
__global__ void k_cbnorm(const float* __restrict__ cb, float* __restrict__ en,
                         float* __restrict__ enorm2, short* __restrict__ enh) {
    __shared__ double wsum[4];
    const int k = blockIdx.x, c = threadIdx.x;
    float v = cb[(size_t)k * CC + c];
    double d = (double)v * (double)v;
#pragma unroll
    for (int m = 32; m >= 1; m >>= 1) d += __shfl_down(d, m);
    const int wv = c >> 6, ln = c & 63;
    if (ln == 0) wsum[wv] = d;
    __syncthreads();
    const double tot = wsum[0] + wsum[1] + wsum[2] + wsum[3];
    const float s32 = (float)tot;
    const float rn = 1.0f / sqrtf(s32 + 1e-12f);
    const float e = v * rn;                 // one fp32 rounding, like ref
    en[(size_t)k * CC + c] = e;
    enh[(size_t)k * CC + c] = bf16bits(e);
    double e2 = (double)e * (double)e;
#pragma unroll
    for (int m = 32; m >= 1; m >>= 1) e2 += __shfl_down(e2, m);
    __syncthreads();
    if (ln == 0) wsum[wv] = e2;
    __syncthreads();
    if (c == 0) enorm2[k] = (float)(wsum[0] + wsum[1] + wsum[2] + wsum[3]);
}

// ---------- K2 (fused): per-frame fp64 norm + rn + transpose to bf16 xnh
__global__ __launch_bounds__(256, 2) void k_xt2(
    const float* __restrict__ x, float* __restrict__ rnx,
    float* __restrict__ nxn, short* __restrict__ xnh) {
    __shared__ short T[64][260];
    __shared__ double red[4][64];
    __shared__ float rns[64];
    const int tid = threadIdx.x;
    const int b = blockIdx.x >> 6;
    const int l0 = (blockIdx.x & 63) << 6;
    const int l = tid & 63, seg = tid >> 6;
    const float* xp = x + (size_t)b * CC * LL + l0 + l;

    double s0 = 0.0, s1 = 0.0, s2 = 0.0, s3 = 0.0;
#pragma unroll 4
    for (int i = 0; i < 64; i += 4) {
        int c = seg * 64 + i;
        float v0 = xp[(size_t)(c + 0) * LL];
        float v1 = xp[(size_t)(c + 1) * LL];
        float v2 = xp[(size_t)(c + 2) * LL];
        float v3 = xp[(size_t)(c + 3) * LL];
        s0 += (double)v0 * v0; s1 += (double)v1 * v1;
        s2 += (double)v2 * v2; s3 += (double)v3 * v3;
    }
    red[seg][l] = (s0 + s1) + (s2 + s3);
    __syncthreads();
    if (tid < 64) {
        double tot = (red[0][tid] + red[1][tid]) + (red[2][tid] + red[3][tid]);
        const float s32 = (float)tot;
        const float rn = 1.0f / sqrtf(s32 + 1e-12f);
        const int f = b * LL + l0 + tid;
        rnx[f] = rn;
        nxn[f] = s32 * rn * rn;
        rns[tid] = rn;
    }
    __syncthreads();
    const float rn = rns[l];

#pragma unroll 8
    for (int i = 0; i < 64; ++i) {
        int c = seg * 64 + i;
        T[l][c] = bf16bits(xp[(size_t)c * LL] * rn);
    }
    __syncthreads();
#pragma unroll
    for (int rr = 0; rr < 4; ++rr) {
        int row = rr * 16 + (tid >> 4);
        int cs = (tid & 15) << 4;
        short* dst = xnh + ((size_t)(b * LL + l0 + row)) * 256 + cs;
        short4v p0 = *(const short4v*)&T[row][cs + 0];
        short4v p1 = *(const short4v*)&T[row][cs + 4];
        short4v p2 = *(const short4v*)&T[row][cs + 8];
        short4v p3 = *(const short4v*)&T[row][cs + 12];
        short8v o0, o1;
        o0[0]=p0[0];o0[1]=p0[1];o0[2]=p0[2];o0[3]=p0[3];o0[4]=p1[0];o0[5]=p1[1];o0[6]=p1[2];o0[7]=p1[3];
        o1[0]=p2[0];o1[1]=p2[1];o1[2]=p2[2];o1[3]=p2[3];o1[4]=p3[0];o1[5]=p3[1];o1[6]=p3[2];o1[7]=p3[3];
        *(short8v*)&dst[0] = o0;
        *(short8v*)&dst[8] = o1;
    }
}

// ---------------- K3: bf16 MFMA sim GEMM -> block-local LDS candidate queue
// 64 frames x 1024 k per block. Barrier-free main loop; B pipelined with a
// 3-deep register ring at issue distance 2 (covers ~200-300cy L2 latency).
// Flush: per-frame TRUE max over queue, filter to sim >= fmax - BAND.
#define BLOADF(dst, s)                                                         \
    {                                                                          \
        const int kcv = (s) >> 3, csv = (s) & 7;                               \
        _Pragma("unroll")                                                      \
        for (int kt = 0; kt < 4; ++kt)                                         \
            dst[kt] = *(const short8v*)&enh[(size_t)(kcv * 256 + w * 64 +      \
                                                     kt * 16 + lr) * 256 +     \
                                            csv * 32 + lg * 8];                \
    }

__global__ __launch_bounds__(256, 2) void k_cand(
    const short* __restrict__ xnh, const short* __restrict__ enh,
    int* __restrict__ qcnt, int* __restrict__ fcnt,
    unsigned short* __restrict__ qbuf) {
    __shared__ short Alds[64 * 256];       // 32KB, swizzled ^((fr&7)<<3)
    __shared__ unsigned short qd[QCAP];    // 4KB  (fl<<10)|k
    __shared__ float qs[QCAP];             // 8KB  fp32 sims
    __shared__ unsigned int fmaxu[64];
    __shared__ int qn, fn;
    const int tid = threadIdx.x;
    const int w = tid >> 6;
    const int l = tid & 63;
    const int lr = l & 15, lg = l >> 4;
    const int b = blockIdx.x >> 6;
    const int l0 = (blockIdx.x & 63) << 6;
    const int f0 = b * LL + l0;

    // ---- stage A once: 64f x 256c
    {
        short8v areg[8];
#pragma unroll
        for (int i = 0; i < 8; ++i) {
            int idx = i * 256 + tid;
            int fr = idx >> 5, c8 = (idx & 31) << 3;
            areg[i] = *(const short8v*)&xnh[(size_t)(f0 + fr) * 256 + c8];
        }
#pragma unroll
        for (int i = 0; i < 8; ++i) {
            int idx = i * 256 + tid;
            int fr = idx >> 5, c8 = (idx & 31) << 3;
            *(short8v*)&Alds[(fr * 256 + c8) ^ ((fr & 7) << 3)] = areg[i];
        }
    }
    if (tid == 0) { qn = 0; fn = 0; }
    if (tid < 64) fmaxu[tid] = 0;
    __syncthreads();          // the ONLY pre-flush barrier

    float runmax[4][4];
#pragma unroll
    for (int i = 0; i < 4; ++i)
#pragma unroll
        for (int r = 0; r < 4; ++r) runmax[i][r] = -3e38f;

    float acc[4][4][4];       // [ft][kt][r], zeroed at each kc start
    short8v breg[3][4];       // 3-deep ring
    BLOADF(breg[0], 0);
    BLOADF(breg[1], 1);

#pragma unroll
    for (int s = 0; s < 32; ++s) {
        const int kc = s >> 3, cs = s & 7;
        const int cur = s % 3;
        if (cs == 0) {
#pragma unroll
            for (int ft = 0; ft < 4; ++ft)
#pragma unroll
                for (int kt = 0; kt < 4; ++kt)
#pragma unroll
                    for (int r = 0; r < 4; ++r) acc[ft][kt][r] = 0.f;
        }
        if (s + 2 < 32) {
            BLOADF(breg[(s + 2) % 3], s + 2);   // issue distance 2
        }
        short8v af[4];
#pragma unroll
        for (int ft = 0; ft < 4; ++ft) {
            int fr = ft * 16 + lr;
            af[ft] = *(const short8v*)&Alds[(fr * 256 + cs * 32 + lg * 8) ^ ((lr & 7) << 3)];
        }
#pragma unroll
        for (int kt = 0; kt < 4; ++kt) {
#pragma unroll
            for (int ft = 0; ft < 4; ++ft) {
                f32x4 a4 = {acc[ft][kt][0], acc[ft][kt][1], acc[ft][kt][2], acc[ft][kt][3]};
                a4 = mfma16(af[ft], breg[cur][kt], a4);
                acc[ft][kt][0] = a4[0]; acc[ft][kt][1] = a4[1];
                acc[ft][kt][2] = a4[2]; acc[ft][kt][3] = a4[3];
            }
        }

        if (cs == 7) {
            // ---- epilogue: wave-local prefix max + banded LDS-queue appends
#pragma unroll
            for (int ft = 0; ft < 4; ++ft) {
#pragma unroll
                for (int r = 0; r < 4; ++r) {
                    float m = fmaxf(fmaxf(acc[ft][0][r], acc[ft][1][r]),
                                    fmaxf(acc[ft][2][r], acc[ft][3][r]));
#pragma unroll
                    for (int mm = 1; mm < 16; mm <<= 1) m = fmaxf(m, __shfl_xor(m, mm));
                    float rm = fmaxf(runmax[ft][r], m);
                    runmax[ft][r] = rm;
                    const float thr = rm - BAND;
                    const int fl = ft * 16 + lg * 4 + r;
#pragma unroll
                    for (int kt = 0; kt < 4; ++kt) {
                        if (acc[ft][kt][r] >= thr) {
                            int kg = kc * 256 + w * 64 + kt * 16 + lr;
                            int slot = atomicAdd(&qn, 1);          // LDS atomic
                            if (slot < QCAP) {
                                qd[slot] = (unsigned short)((fl << 10) | kg);
                                qs[slot] = acc[ft][kt][r];
                            }
                        }
                    }
                }
            }
        }
    }

    // ---- flush: per-frame TRUE max over queue, filter, write direct
    __syncthreads();
    const int n = qn;
    if (tid == 0) qcnt[blockIdx.x] = n;
    if (n > QCAP) return;     // overflow (~never): fallback3 does full scan
    for (int i = tid; i < n; i += 256)
        atomicMax(&fmaxu[qd[i] >> 10], fflip(qs[i]));
    __syncthreads();
    for (int i = tid; i < n; i += 256) {
        const float fm = funflip(fmaxu[qd[i] >> 10]);
        if (qs[i] >= fm - BAND) {
            int s = atomicAdd(&fn, 1);
            qbuf[(size_t)blockIdx.x * QCAP + s] = qd[i];
        }
    }
    __syncthreads();
    if (tid == 0) fcnt[blockIdx.x] = fn;
}

// --------- K4: LDS-staged seq-fp32 re-check of the block queue + atomic key
__global__ __launch_bounds__(256, 2) void k_resolve2(
    const float* __restrict__ x, const float* __restrict__ en,
    const float* __restrict__ rnx, const int* __restrict__ qcnt,
    const int* __restrict__ fcnt, const unsigned short* __restrict__ qbuf,
    unsigned long long* __restrict__ pk) {
    __shared__ float xn[64 * 257];
    __shared__ float rns[64];
    const int tid = threadIdx.x;
    const int bid = blockIdx.x;
    const int b = bid >> 6;
    const int l0 = (bid & 63) << 6;
    const int f0 = b * LL + l0;
    const float* xb = x + (size_t)b * CC * LL + l0;

    if (qcnt[bid] > QCAP) return;      // overflow block -> k_fallback3 (uniform)
    const int n = fcnt[bid];

    if (tid < 64) rns[tid] = rnx[f0 + tid];
    __syncthreads();
    // vectorized stage: float4 over l (16B/lane)
    {
        const int lt = tid & 15, l4 = lt << 2;
        const float r0 = rns[l4 + 0], r1 = rns[l4 + 1];
        const float r2 = rns[l4 + 2], r3 = rns[l4 + 3];
#pragma unroll 4
        for (int it = 0; it < 16; ++it) {
            const int c = it * 16 + (tid >> 4);
            f32x4 v = *(const f32x4*)&xb[(size_t)c * LL + l4];
            xn[(l4 + 0) * 257 + c] = v[0] * r0;
            xn[(l4 + 1) * 257 + c] = v[1] * r1;
            xn[(l4 + 2) * 257 + c] = v[2] * r2;
            xn[(l4 + 3) * 257 + c] = v[3] * r3;
        }
    }
    __syncthreads();
    for (int e = tid; e < n; e += 256) {
        const unsigned short ent = qbuf[(size_t)bid * QCAP + e];
        const int fl = ent >> 10, k = ent & 1023;
        const f32x4* er4 = (const f32x4*)(en + (size_t)k * CC);
        const float* xr = &xn[fl * 257];
        float s = 0.f;
#pragma unroll 8
        for (int c4 = 0; c4 < 64; ++c4) {      // ascending c, sequential FMA
            f32x4 ev = er4[c4];
            s = fmaf(xr[c4 * 4 + 0], ev[0], s);
            s = fmaf(xr[c4 * 4 + 1], ev[1], s);
            s = fmaf(xr[c4 * 4 + 2], ev[2], s);
            s = fmaf(xr[c4 * 4 + 3], ev[3], s);
        }
        atomicMax(&pk[f0 + fl], packkey(s, k));
    }
}

// -------- K4b: queue-overflow fallback (~never): full scan of block's frames
__global__ __launch_bounds__(256) void k_fallback3(
    const float* __restrict__ x, const float* __restrict__ en,
    const float* __restrict__ rnx, const int* __restrict__ qcnt,
    unsigned long long* __restrict__ pk) {
    if (qcnt[blockIdx.x] <= QCAP) return;      // block-uniform early exit
    __shared__ float xr[CC];
    const int tid = threadIdx.x;
    const int b = blockIdx.x >> 6;
    const int l0 = (blockIdx.x & 63) << 6;
    for (int fl = 0; fl < 64; ++fl) {
        const int f = b * LL + l0 + fl;
        __syncthreads();
        xr[tid] = x[((size_t)b * CC + tid) * LL + (l0 + fl)] * rnx[f];
        __syncthreads();
#pragma unroll
        for (int j = 0; j < 4; ++j) {
            const int k = tid + j * 256;
            const f32x4* er4 = (const f32x4*)(en + (size_t)k * CC);
            float s = 0.f;
#pragma unroll 8
            for (int c4 = 0; c4 < 64; ++c4) {
                f32x4 ev = er4[c4];
                s = fmaf(xr[c4 * 4 + 0], ev[0], s);
                s = fmaf(xr[c4 * 4 + 1], ev[1], s);
                s = fmaf(xr[c4 * 4 + 2], ev[2], s);
                s = fmaf(xr[c4 * 4 + 3], ev[3], s);
            }
            atomicMax(&pk[f], packkey(s, k));
        }
    }
}

// ---------------- K5: unpack winners, gather -> out, loss reduce
__global__ void k_gather(const float* __restrict__ en,
                         const unsigned long long* __restrict__ pk,
                         const float* __restrict__ nxn,
                         const float* __restrict__ enorm2, float* __restrict__ out,
                         float* __restrict__ loss) {
    __shared__ float ens[32][257];
    __shared__ int lidx[32];
    __shared__ float ssim[32];
    const int tid = threadIdx.x;
    const int b = blockIdx.x >> 7;
    const int l0 = (blockIdx.x & 127) << 5;
    const int fbase = b * LL + l0;
    if (tid < 32) {
        unsigned long long v = pk[fbase + tid];
        lidx[tid] = 1023 - (int)(v & 1023ull);
        unsigned int hi = (unsigned int)(v >> 32);
        unsigned int sb = (hi & 0x80000000u) ? (hi ^ 0x80000000u) : ~hi;
        ssim[tid] = __uint_as_float(sb);
    }
    __syncthreads();
    for (int j = 0; j < 32; ++j)
        ens[j][tid] = en[(size_t)lidx[j] * CC + tid];
    __syncthreads();
    const int jj = tid & 31;
    const int c0 = (tid >> 5) << 5;
    float* ob = out + (size_t)b * CC * LL + l0;
#pragma unroll 4
    for (int ci = 0; ci < 32; ++ci) {
        int c = c0 + ci;
        ob[(size_t)c * LL + jj] = ens[jj][c];
    }
    float part = 0.f;
    if (tid < 32) {
        int f = fbase + tid;
        part = nxn[f] + enorm2[lidx[tid]] - 2.0f * ssim[tid];
    }
    if (tid < 64) {
#pragma unroll
        for (int m = 32; m >= 1; m >>= 1) part += __shfl_xor(part, m);
        if (tid == 0) atomicAdd(loss, part * (1.25f / 16777216.f));
    }
}

// ------------------------------------------------------------------- launch
extern "C" void kernel_launch(void* const* d_in, const int* in_sizes, int n_in,
                              void* d_out, int out_size, void* d_ws, size_t ws_size,
                              hipStream_t stream) {
    const float* x = (const float*)d_in[0];
    const float* cb = (const float*)d_in[1];
    float* out = (float*)d_out;
    char* ws = (char*)d_ws;
    char* ob = (char*)d_out;

    // ws scratch (~2.7 MB)
    float* en     = (float*)(ws);                    // 1 MB
    float* enorm2 = (float*)(ws + 0x100000);         // 4 KB
    float* rnx    = (float*)(ws + 0x101000);         // 256 KB
    float* nxn    = (float*)(ws + 0x141000);         // 256 KB
    short* enh    = (short*)(ws + 0x181000);         // 512 KB
    unsigned long long* pk = (unsigned long long*)(ws + 0x201000);  // 512 KB
    int*   qcnt   = (int*)(ws + 0x281000);           // 4 KB
    int*   fcnt   = (int*)(ws + 0x282000);           // 4 KB

    // big scratch inside d_out (64 MB); gather (last) overwrites it.
    short*          xnh  = (short*)ob;                       // 32 MB
    unsigned short* qbuf = (unsigned short*)(ob + 33554432); // 4 MB (1024*QCAP*2B)

    hipMemsetAsync(pk, 0, NFRM * sizeof(unsigned long long), stream);
    hipMemsetAsync(out + NOUT, 0, sizeof(float), stream);

    k_cbnorm<<<KNUM, 256, 0, stream>>>(cb, en, enorm2, enh);
    k_xt2<<<BB * (LL / 64), 256, 0, stream>>>(x, rnx, nxn, xnh);
    k_cand<<<BB * (LL / 64), 256, 0, stream>>>(xnh, enh, qcnt, fcnt, qbuf);
    k_resolve2<<<BB * (LL / 64), 256, 0, stream>>>(x, en, rnx, qcnt, fcnt, qbuf, pk);
    k_fallback3<<<BB * (LL / 64), 256, 0, stream>>>(x, en, rnx, qcnt, pk);
    k_gather<<<BB * (LL / 32), 256, 0, stream>>>(en, pk, nxn, enorm2, out, out + NOUT);
}

// Round 14
// 149.344 us; speedup vs baseline: 1.6314x; 1.4185x over previous
//
#include <hip/hip_runtime.h>
#include <hip/hip_bf16.h>
#include <cstdint>
#include <cstddef>

#define BB 16
#define CC 256
#define LL 4096
#define KNUM 1024
#define NFRM (BB * LL)      // 65536 frames
#define QCAP 1536           // block-local candidate queue capacity
#define BAND 0.012f

static const size_t NOUT = (size_t)BB * CC * LL;   // 16777216 floats

typedef __attribute__((ext_vector_type(8))) short short8v;
typedef __attribute__((ext_vector_type(4))) float f32x4;
typedef __attribute__((ext_vector_type(8))) __bf16 bf16x8;

__device__ __forceinline__ f32x4 mfma16(short8v a, short8v b, f32x4 c) {
    return __builtin_amdgcn_mfma_f32_16x16x32_bf16(
        __builtin_bit_cast(bf16x8, a), __builtin_bit_cast(bf16x8, b), c, 0, 0, 0);
}

__device__ __forceinline__ short bf16bits(float v) {
    __hip_bfloat16 h = __float2bfloat16(v);
    return *reinterpret_cast<short*>(&h);
}

// pack (sim, k) so that u64-max == (greater sim, else lower k)
__device__ __forceinline__ unsigned long long packkey(float s, int k) {
    unsigned int sb = __float_as_uint(s);
    sb = (sb & 0x80000000u) ? ~sb : (sb | 0x80000000u);
    return ((unsigned long long)sb << 32) | (unsigned long long)(1023 - k);
}

// ------------------------------------------------------- K1: codebook norms
// BYTE-IDENTICAL math to rounds 3-13.
__global__ void k_cbnorm(const float* __restrict__ cb, float* __restrict__ en,
                         float* __restrict__ enorm2, short* __restrict__ enh) {
    __shared__ double wsum[4];
    const int k = blockIdx.x, c = threadIdx.x;
    float v = cb[(size_t)k * CC + c];
    double d = (double)v * (double)v;
#pragma unroll
    for (int m = 32; m >= 1; m >>= 1) d += __shfl_down(d, m);
    const int wv = c >> 6, ln = c & 63;
    if (ln == 0) wsum[wv] = d;
    __syncthreads();
    const double tot = wsum[0] + wsum[1] + wsum[2] + wsum[3];
    const float s32 = (float)tot;
    const float rn = 1.0f / sqrtf(s32 + 1e-12f);
    const float e = v * rn;                 // one fp32 rounding, like ref
    en[(size_t)k * CC + c] = e;
    enh[(size_t)k * CC + c] = bf16bits(e);
    double e2 = (double)e * (double)e;
#pragma unroll
    for (int m = 32; m >= 1; m >>= 1) e2 += __shfl_down(e2, m);
    __syncthreads();
    if (ln == 0) wsum[wv] = e2;
    __syncthreads();
    if (c == 0) enorm2[k] = (float)(wsum[0] + wsum[1] + wsum[2] + wsum[3]);
}

// ---------------- K2: MEGA — norms + A-stage + GEMM/queue + resolve + gather
#define BLOAD(dst, kcv, csv)                                                   \
    _Pragma("unroll")                                                          \
    for (int kt = 0; kt < 4; ++kt)                                             \
        dst[kt] = *(const short8v*)&enh[(size_t)((kcv) * 256 + w * 64 +        \
                                                 kt * 16 + lr) * 256 +         \
                                        (csv) * 32 + lg * 8];

__global__ __launch_bounds__(256, 2) void k_mega(
    const float* __restrict__ x, const float* __restrict__ en,
    const float* __restrict__ enorm2, const short* __restrict__ enh,
    float* __restrict__ out, float* __restrict__ loss) {
    __shared__ char U[64 * 257 * 4];       // union: A bf16[64x256] / xn f32[64x257] / ens
    __shared__ double red[4][64];
    __shared__ float rns_l[64];
    __shared__ float nxn_l[64];
    __shared__ unsigned short qd[QCAP];
    __shared__ unsigned long long pk_l[64];
    __shared__ float wmax[256];            // [w][ft][lg][r]
    __shared__ int qn;

    short* A = (short*)U;
    float* xn = (float*)U;

    const int tid = threadIdx.x;
    const int w = tid >> 6;
    const int l = tid & 63;
    const int lr = l & 15, lg = l >> 4;
    const int b = blockIdx.x >> 6;
    const int l0 = (blockIdx.x & 63) << 6;
    const float* xp = x + (size_t)b * CC * LL + l0 + l;

    // ---- phase 1: fp64 norms (EXACT xt2 pass-1 semantics)
    {
        double s0 = 0.0, s1 = 0.0, s2 = 0.0, s3 = 0.0;
#pragma unroll 4
        for (int i = 0; i < 64; i += 4) {
            int c = w * 64 + i;
            float v0 = xp[(size_t)(c + 0) * LL];
            float v1 = xp[(size_t)(c + 1) * LL];
            float v2 = xp[(size_t)(c + 2) * LL];
            float v3 = xp[(size_t)(c + 3) * LL];
            s0 += (double)v0 * v0; s1 += (double)v1 * v1;
            s2 += (double)v2 * v2; s3 += (double)v3 * v3;
        }
        red[w][l] = (s0 + s1) + (s2 + s3);
    }
    __syncthreads();
    if (tid < 64) {
        double tot = (red[0][tid] + red[1][tid]) + (red[2][tid] + red[3][tid]);
        const float s32 = (float)tot;
        const float rn = 1.0f / sqrtf(s32 + 1e-12f);
        rns_l[tid] = rn;
        nxn_l[tid] = s32 * rn * rn;
        pk_l[tid] = 0ull;
    }
    if (tid == 0) qn = 0;
    __syncthreads();

    // ---- phase 2: bf16 convert + transpose A into LDS (swizzled) — L2-hot re-read
    {
        const float rn = rns_l[l];
#pragma unroll
        for (int i8 = 0; i8 < 8; ++i8) {
            int cb = w * 64 + i8 * 8;
            short8v o;
#pragma unroll
            for (int j = 0; j < 8; ++j)
                o[j] = bf16bits(xp[(size_t)(cb + j) * LL] * rn);
            *(short8v*)&A[(l * 256 + cb) ^ ((l & 7) << 3)] = o;
        }
    }
    __syncthreads();

    // ---- phase 3: GEMM + candidate queue (r9 structure, verbatim)
    float runmax[4][4];
#pragma unroll
    for (int i = 0; i < 4; ++i)
#pragma unroll
        for (int r = 0; r < 4; ++r) runmax[i][r] = -3e38f;

    short8v breg[2][4];
    BLOAD(breg[0], 0, 0);

    for (int kc = 0; kc < 4; ++kc) {
        f32x4 acc[4][4];
#pragma unroll
        for (int ft = 0; ft < 4; ++ft)
#pragma unroll
            for (int kt = 0; kt < 4; ++kt) acc[ft][kt] = (f32x4){0.f, 0.f, 0.f, 0.f};

#pragma unroll
        for (int cs = 0; cs < 8; ++cs) {
            const int cur = cs & 1, nxt = cur ^ 1;
            if (cs < 7) {
                BLOAD(breg[nxt], kc, cs + 1);
            } else if (kc < 3) {
                BLOAD(breg[nxt], kc + 1, 0);
            }
            short8v af[4];
#pragma unroll
            for (int ft = 0; ft < 4; ++ft) {
                int fr = ft * 16 + lr;
                af[ft] = *(const short8v*)&A[(fr * 256 + cs * 32 + lg * 8) ^ ((lr & 7) << 3)];
            }
#pragma unroll
            for (int kt = 0; kt < 4; ++kt)
#pragma unroll
                for (int ft = 0; ft < 4; ++ft)
                    acc[ft][kt] = mfma16(af[ft], breg[cur][kt], acc[ft][kt]);
        }

        // ---- epilogue: cross-wave global prefix max + banded LDS-queue appends
        float mloc[4][4];
#pragma unroll
        for (int ft = 0; ft < 4; ++ft)
#pragma unroll
            for (int r = 0; r < 4; ++r) {
                float m = fmaxf(fmaxf(acc[ft][0][r], acc[ft][1][r]),
                                fmaxf(acc[ft][2][r], acc[ft][3][r]));
#pragma unroll
                for (int mm = 1; mm < 16; mm <<= 1) m = fmaxf(m, __shfl_xor(m, mm));
                mloc[ft][r] = m;
            }
        if (lr == 0) {
#pragma unroll
            for (int ft = 0; ft < 4; ++ft)
#pragma unroll
                for (int r = 0; r < 4; ++r)
                    wmax[((w * 4 + ft) * 4 + lg) * 4 + r] = mloc[ft][r];
        }
        __syncthreads();
#pragma unroll
        for (int ft = 0; ft < 4; ++ft) {
#pragma unroll
            for (int r = 0; r < 4; ++r) {
                float gm = fmaxf(
                    fmaxf(wmax[((0 * 4 + ft) * 4 + lg) * 4 + r],
                          wmax[((1 * 4 + ft) * 4 + lg) * 4 + r]),
                    fmaxf(wmax[((2 * 4 + ft) * 4 + lg) * 4 + r],
                          wmax[((3 * 4 + ft) * 4 + lg) * 4 + r]));
                float rm = fmaxf(runmax[ft][r], gm);
                runmax[ft][r] = rm;
                const float thr = rm - BAND;
                const int fl = ft * 16 + lg * 4 + r;
#pragma unroll
                for (int kt = 0; kt < 4; ++kt) {
                    if (acc[ft][kt][r] >= thr) {
                        int kg = kc * 256 + w * 64 + kt * 16 + lr;
                        int slot = atomicAdd(&qn, 1);          // LDS atomic
                        if (slot < QCAP)
                            qd[slot] = (unsigned short)((fl << 10) | kg);
                    }
                }
            }
        }
        __syncthreads();   // wmax reusable next kc; last iter = fence before phase 4
    }

    const int n = qn;

    // ---- phase 4: stage fp32 xn into LDS (A is dead; union reuse), float4 loads
    {
        const float* xb = x + (size_t)b * CC * LL + l0;
        const int l4 = (tid & 15) << 2;
        const float r0 = rns_l[l4 + 0], r1 = rns_l[l4 + 1];
        const float r2 = rns_l[l4 + 2], r3 = rns_l[l4 + 3];
#pragma unroll 4
        for (int it = 0; it < 16; ++it) {
            const int c = it * 16 + (tid >> 4);
            f32x4 v = *(const f32x4*)&xb[(size_t)c * LL + l4];
            xn[(l4 + 0) * 257 + c] = v[0] * r0;
            xn[(l4 + 1) * 257 + c] = v[1] * r1;
            xn[(l4 + 2) * 257 + c] = v[2] * r2;
            xn[(l4 + 3) * 257 + c] = v[3] * r3;
        }
    }
    __syncthreads();

    // ---- phase 5: exact seq-fp32 resolve into LDS packed keys
    if (n <= QCAP) {
        for (int e = tid; e < n; e += 256) {
            const unsigned short ent = qd[e];
            const int fl = ent >> 10, k = ent & 1023;
            const f32x4* er4 = (const f32x4*)(en + (size_t)k * CC);
            const float* xr = &xn[fl * 257];
            float s = 0.f;
#pragma unroll 8
            for (int c4 = 0; c4 < 64; ++c4) {      // ascending c, sequential FMA
                f32x4 ev = er4[c4];
                s = fmaf(xr[c4 * 4 + 0], ev[0], s);
                s = fmaf(xr[c4 * 4 + 1], ev[1], s);
                s = fmaf(xr[c4 * 4 + 2], ev[2], s);
                s = fmaf(xr[c4 * 4 + 3], ev[3], s);
            }
            atomicMax(&pk_l[fl], packkey(s, k));
        }
    } else {
        // overflow (~never): exact full scan, 4 threads per frame x 256 k each
        const int fl = tid >> 2, q = tid & 3;
        const float* xr = &xn[fl * 257];
        unsigned long long best = 0ull;
        for (int k = q * 256; k < q * 256 + 256; ++k) {
            const f32x4* er4 = (const f32x4*)(en + (size_t)k * CC);
            float s = 0.f;
#pragma unroll 8
            for (int c4 = 0; c4 < 64; ++c4) {
                f32x4 ev = er4[c4];
                s = fmaf(xr[c4 * 4 + 0], ev[0], s);
                s = fmaf(xr[c4 * 4 + 1], ev[1], s);
                s = fmaf(xr[c4 * 4 + 2], ev[2], s);
                s = fmaf(xr[c4 * 4 + 3], ev[3], s);
            }
            unsigned long long key = packkey(s, k);
            if (key > best) best = key;
        }
        atomicMax(&pk_l[fl], best);
    }
    __syncthreads();

    // ---- phase 6: gather winner rows (reuse union as ens), write out, loss
    float* ens = xn;
    for (int j = 0; j < 64; ++j) {
        int kwj = 1023 - (int)(pk_l[j] & 1023ull);
        ens[j * 257 + tid] = en[(size_t)kwj * CC + tid];
    }
    __syncthreads();
    {
        float* ob = out + (size_t)b * CC * LL + l0;
        const int fl = tid & 63, cq = tid >> 6;
#pragma unroll 4
        for (int i = 0; i < 64; ++i) {
            int c = cq * 64 + i;
            ob[(size_t)c * LL + fl] = ens[fl * 257 + c];
        }
    }
    if (tid < 64) {
        unsigned long long v = pk_l[tid];
        int kw = 1023 - (int)(v & 1023ull);
        unsigned int hi = (unsigned int)(v >> 32);
        unsigned int sb = (hi & 0x80000000u) ? (hi ^ 0x80000000u) : ~hi;
        float sim = __uint_as_float(sb);
        float part = nxn_l[tid] + enorm2[kw] - 2.0f * sim;
#pragma unroll
        for (int m = 32; m >= 1; m >>= 1) part += __shfl_xor(part, m);
        if (tid == 0) atomicAdd(loss, part * (1.25f / 16777216.f));
    }
}

// ------------------------------------------------------------------- launch
extern "C" void kernel_launch(void* const* d_in, const int* in_sizes, int n_in,
                              void* d_out, int out_size, void* d_ws, size_t ws_size,
                              hipStream_t stream) {
    const float* x = (const float*)d_in[0];
    const float* cb = (const float*)d_in[1];
    float* out = (float*)d_out;
    char* ws = (char*)d_ws;

    // ws scratch (~1.52 MB total)
    float* en     = (float*)(ws);                    // 1 MB
    float* enorm2 = (float*)(ws + 0x100000);         // 4 KB
    short* enh    = (short*)(ws + 0x101000);         // 512 KB

    hipMemsetAsync(out + NOUT, 0, sizeof(float), stream);

    k_cbnorm<<<KNUM, 256, 0, stream>>>(cb, en, enorm2, enh);
    k_mega<<<BB * (LL / 64), 256, 0, stream>>>(x, en, enorm2, enh, out, out + NOUT);
}